// Round 5
// baseline (681.370 us; speedup 1.0000x reference)
//
#include <hip/hip_runtime.h>
#include <hip/hip_bf16.h>
#include <math.h>

#define RR 32
#define R3 32768
#define BB 4
#define CI 64
#define CO 64
#define NN 4096

typedef short v8s __attribute__((ext_vector_type(8)));
typedef float v4f __attribute__((ext_vector_type(4)));
typedef unsigned short ushort_t;

__device__ __forceinline__ unsigned short f2bf(float f) {
    unsigned int u = __float_as_uint(f);
    unsigned int r = (u + 0x7FFFu + ((u >> 16) & 1u)) >> 16;
    return (unsigned short)r;
}

// ---------------- block reduce helpers ----------------
__device__ __forceinline__ float blockReduceSum(float v, float* sm) {
    int tid = threadIdx.x;
    sm[tid] = v; __syncthreads();
    for (int off = 128; off > 0; off >>= 1) {
        if (tid < off) sm[tid] += sm[tid + off];
        __syncthreads();
    }
    float r = sm[0]; __syncthreads();
    return r;
}
__device__ __forceinline__ float blockReduceMax(float v, float* sm) {
    int tid = threadIdx.x;
    sm[tid] = v; __syncthreads();
    for (int off = 128; off > 0; off >>= 1) {
        if (tid < off) sm[tid] = fmaxf(sm[tid], sm[tid + off]);
        __syncthreads();
    }
    float r = sm[0]; __syncthreads();
    return r;
}

// ---------------- voxel coords ----------------
__global__ void k_nc(const float* __restrict__ coords, float* __restrict__ nc,
                     int* __restrict__ vidx) {
    int b = blockIdx.x, tid = threadIdx.x;
    __shared__ float sm[256];
    const float* cb = coords + (size_t)b * 3 * NN;
    float s0 = 0, s1 = 0, s2 = 0;
    for (int n = tid; n < NN; n += 256) {
        s0 += cb[n]; s1 += cb[NN + n]; s2 += cb[2 * NN + n];
    }
    float m0 = blockReduceSum(s0, sm) * (1.0f / NN);
    float m1 = blockReduceSum(s1, sm) * (1.0f / NN);
    float m2 = blockReduceSum(s2, sm) * (1.0f / NN);
    float mx = 0;
    for (int n = tid; n < NN; n += 256) {
        float dx = cb[n] - m0, dy = cb[NN + n] - m1, dz = cb[2 * NN + n] - m2;
        mx = fmaxf(mx, dx * dx + dy * dy + dz * dz);
    }
    mx = blockReduceMax(mx, sm);
    float denom = 2.0f * sqrtf(mx);
    float mean[3] = {m0, m1, m2};
    for (int n = tid; n < NN; n += 256) {
        int vi[3];
        #pragma unroll
        for (int ax = 0; ax < 3; ax++) {
            float x = (cb[ax * NN + n] - mean[ax]) / denom + 0.5f;
            x = x * RR;
            x = fminf(fmaxf(x, 0.0f), (float)(RR - 1));
            nc[((size_t)b * 3 + ax) * NN + n] = x;
            vi[ax] = (int)rintf(x);
        }
        vidx[b * NN + n] = (vi[0] * RR + vi[1]) * RR + vi[2];
    }
}

// ---------------- scatter-mean (channel-last grid) ----------------
__global__ void k_scatter(const float* __restrict__ feat, const int* __restrict__ vidx,
                          float* __restrict__ grid, float* __restrict__ cnt) {
    int tid = threadIdx.x;
    int pid = blockIdx.x * 64 + (tid & 63);
    int cg = tid >> 6;
    int b = pid / NN, n = pid % NN;
    int idx = vidx[pid];
    if (cg == 0) atomicAdd(&cnt[b * R3 + idx], 1.0f);
    float* gdst = grid + ((size_t)b * R3 + idx) * 64;
    #pragma unroll 4
    for (int c = cg * 16; c < cg * 16 + 16; c++)
        atomicAdd(&gdst[c], feat[((size_t)(b * CI + c)) * NN + n]);
}

// ---------------- divide-by-count + bf16 cast (cl -> cl) ----------------
__global__ void k_avg2(const float* __restrict__ grid, const float* __restrict__ cnt,
                       ushort_t* __restrict__ gT) {
    size_t i = (size_t)blockIdx.x * 256 + threadIdx.x;  // over B*R3*64/8
    int b = (int)(i >> 18);
    int v = (int)((i >> 3) & (R3 - 1));
    float inv = 1.0f / fmaxf(cnt[b * R3 + v], 1.0f);
    float4 a = ((const float4*)grid)[i * 2];
    float4 d = ((const float4*)grid)[i * 2 + 1];
    union { __hip_bfloat162 h[4]; uint4 u; } pk;
    pk.h[0] = __float22bfloat162_rn(make_float2(a.x * inv, a.y * inv));
    pk.h[1] = __float22bfloat162_rn(make_float2(a.z * inv, a.w * inv));
    pk.h[2] = __float22bfloat162_rn(make_float2(d.x * inv, d.y * inv));
    pk.h[3] = __float22bfloat162_rn(make_float2(d.z * inv, d.w * inv));
    ((uint4*)gT)[i] = pk.u;
}

// ---------------- features f32 -> bf16 (same [b][c][n] layout) ----------------
__global__ void k_f2b(const float* __restrict__ x, ushort_t* __restrict__ o) {
    size_t i = (size_t)blockIdx.x * 256 + threadIdx.x;  // over B*64*NN/8
    float4 a = ((const float4*)x)[i * 2];
    float4 b = ((const float4*)x)[i * 2 + 1];
    union { __hip_bfloat162 h[4]; uint4 u; } pk;
    pk.h[0] = __float22bfloat162_rn(make_float2(a.x, a.y));
    pk.h[1] = __float22bfloat162_rn(make_float2(a.z, a.w));
    pk.h[2] = __float22bfloat162_rn(make_float2(b.x, b.y));
    pk.h[3] = __float22bfloat162_rn(make_float2(b.z, b.w));
    ((uint4*)o)[i] = pk.u;
}

// ---------------- weight transform: wB[k][co][ci] bf16 ----------------
__global__ void k_twb(const float* __restrict__ w, ushort_t* __restrict__ wB) {
    int i = blockIdx.x * 256 + threadIdx.x;  // 27*64*64 = 110592
    int ci = i & 63, t = i >> 6;
    int co = t & 63, k = t >> 6;
    wB[i] = f2bf(w[((size_t)co * CI + ci) * 27 + k]);
}

// ---------------- BN + lrelu + bf16 cast (cl -> cl, no transpose) ----------------
__global__ void k_bncast(const float* __restrict__ x, const float* __restrict__ stats,
                         float slope, ushort_t* __restrict__ o) {
    size_t i = (size_t)blockIdx.x * 256 + threadIdx.x;  // over B*R3*64/8
    int c0 = (int)((i * 8) & 63);
    float4 a = ((const float4*)x)[i * 2];
    float4 d = ((const float4*)x)[i * 2 + 1];
    float va[8] = {a.x, a.y, a.z, a.w, d.x, d.y, d.z, d.w};
    unsigned pk[4];
    #pragma unroll
    for (int j = 0; j < 4; j++) {
        float u0 = va[2 * j] * stats[2 * (c0 + 2 * j)] + stats[2 * (c0 + 2 * j) + 1];
        float u1 = va[2 * j + 1] * stats[2 * (c0 + 2 * j) + 2] + stats[2 * (c0 + 2 * j) + 3];
        u0 = u0 > 0 ? u0 : slope * u0;
        u1 = u1 > 0 ? u1 : slope * u1;
        pk[j] = (unsigned)f2bf(u0) | ((unsigned)f2bf(u1) << 16);
    }
    ((uint4*)o)[i] = make_uint4(pk[0], pk[1], pk[2], pk[3]);
}

// ---------------- MFMA conv3d 3x3x3 v3 (co-split, depth-3 prefetch, XCD swizzle, cl out) ----
#define LOADB(ks, BR)                                                           \
  do {                                                                          \
    int _k = (ks) >> 1, _cih = (ks) & 1;                                        \
    int _dz = _k / 9, _rr = _k % 9, _dy = _rr / 3, _dx = _rr % 3;               \
    unsigned _off = (unsigned)((_dz * 1024 + _dy * 32 + _dx) * 64 + _cih * 32); \
    _Pragma("unroll") for (int _f = 0; _f < 4; _f++)                            \
        BR[_f] = *(const v8s*)(sb[_f] + (lo[_f] + _off));                       \
  } while (0)

#define LOADA(ks, AR)                                                           \
  do {                                                                          \
    int _k = (ks) >> 1, _cih = (ks) & 1;                                        \
    unsigned _offw = (unsigned)(_k * 4096 + _cih * 32);                         \
    _Pragma("unroll") for (int _m = 0; _m < 2; _m++)                            \
        AR[_m] = *(const v8s*)(wB + (loA[_m] + _offw));                         \
  } while (0)

#define MFMAKS(ks, AR, BR)                                                      \
  do {                                                                          \
    int _k = (ks) >> 1;                                                         \
    int _dz = _k / 9, _rr = _k % 9, _dy = _rr / 3, _dx = _rr % 3;               \
    bool _zok = (unsigned)(z0 + _dz - 1) < 32u;                                 \
    v8s _bm[4];                                                                 \
    _Pragma("unroll") for (int _f = 0; _f < 4; _f++) {                          \
      bool _yok = (unsigned)(yw0 + (_f >> 1) + _dy - 1) < 32u;                  \
      bool _xok = (unsigned)((_f & 1) * 16 + l15 + _dx - 1) < 32u;              \
      _bm[_f] = (_zok && _yok && _xok) ? BR[_f] : vzero;                        \
    }                                                                           \
    _Pragma("unroll") for (int _m = 0; _m < 2; _m++)                            \
      _Pragma("unroll") for (int _f = 0; _f < 4; _f++)                          \
        acc[_m][_f] = __builtin_amdgcn_mfma_f32_16x16x32_bf16(AR[_m], _bm[_f],  \
                                                              acc[_m][_f], 0, 0, 0); \
  } while (0)

__global__ __launch_bounds__(256) void k_convm(const ushort_t* __restrict__ gT,
                                               const ushort_t* __restrict__ wB,
                                               float* __restrict__ outCL) {
    // XCD-bijective swizzle: 1024 blocks, 8 XCDs x 128 contiguous wgids
    // wgid = ((b*32 + z0)*4 + yt)*2 + cob  -> each XCD: 16 z-planes of one b (2.4MB L2 set)
    int bid = blockIdx.x;
    int wgid = (bid & 7) * 128 + (bid >> 3);
    int cob = wgid & 1, yt = (wgid >> 1) & 3, z0 = (wgid >> 3) & 31, b = wgid >> 8;
    int tid = threadIdx.x;
    int w = __builtin_amdgcn_readfirstlane(tid >> 6);
    int lane = tid & 63, l15 = lane & 15, l4 = lane >> 4;
    int yw0 = yt * 8 + w * 2;

    const ushort_t* gTb = gT + (size_t)b * R3 * 64;
    const ushort_t* sb[4];
    unsigned lo[4], loA[2];
    #pragma unroll
    for (int f = 0; f < 4; f++) {
        sb[f] = gTb + ((z0 - 1) * 1024 + (yw0 + (f >> 1) - 1) * 32 - 1) * 64;
        lo[f] = (unsigned)((((f & 1) * 16 + l15) * 64) + l4 * 8);
    }
    #pragma unroll
    for (int m = 0; m < 2; m++)
        loA[m] = (unsigned)(((cob * 32 + m * 16 + l15) * 64) + l4 * 8);

    const v8s vzero = {};
    v4f acc[2][4];
    #pragma unroll
    for (int m = 0; m < 2; m++)
        #pragma unroll
        for (int f = 0; f < 4; f++)
            acc[m][f] = (v4f){0.0f, 0.0f, 0.0f, 0.0f};

    v8s Bb[3][4], Ab[2][2];
    LOADB(0, Bb[0]); LOADA(0, Ab[0]);
    LOADB(1, Bb[1]); LOADA(1, Ab[1]);
    LOADB(2, Bb[2]);
    #pragma unroll
    for (int t = 0; t < 54; t++) {
        MFMAKS(t, Ab[t & 1], Bb[t % 3]);
        if (t + 3 < 54) LOADB(t + 3, Bb[t % 3]);
        if (t + 2 < 54) LOADA(t + 2, Ab[t & 1]);
    }

    // D: col(lane&15)=x, row((lane>>4)*4+r)=co-within-16. Channel-last float4 stores.
    #pragma unroll
    for (int m = 0; m < 2; m++) {
        #pragma unroll
        for (int f = 0; f < 4; f++) {
            int y = yw0 + (f >> 1);
            int x = (f & 1) * 16 + l15;
            float4 o = make_float4(acc[m][f][0], acc[m][f][1], acc[m][f][2], acc[m][f][3]);
            *(float4*)&outCL[((size_t)b * R3 + z0 * 1024 + y * 32 + x) * 64 +
                             cob * 32 + m * 16 + l4 * 4] = o;
        }
    }
}

// ---------------- BN stats, channel-last ([B][R3][64]) ----------------
__global__ void k_bnstat_cl(const float* __restrict__ x, float* __restrict__ pst) {
    int slab = blockIdx.x, b = blockIdx.y, tid = threadIdx.x;  // 32 slabs x B
    int c = tid & 63, r = tid >> 6;
    const float* xb = x + ((size_t)b * R3 + slab * 1024) * 64;
    float s = 0, q = 0;
    for (int i = r; i < 1024; i += 4) {
        float v = xb[(size_t)i * 64 + c];
        s += v; q += v * v;
    }
    __shared__ float rs[256], rq[256];
    rs[tid] = s; rq[tid] = q; __syncthreads();
    if (tid < 64) {
        s = rs[tid] + rs[tid + 64] + rs[tid + 128] + rs[tid + 192];
        q = rq[tid] + rq[tid + 64] + rq[tid + 128] + rq[tid + 192];
        int j = b * 32 + slab;  // nb = 128 partials per channel
        pst[(tid * 128 + j) * 2] = s;
        pst[(tid * 128 + j) * 2 + 1] = q;
    }
}

// ---------------- BN stats (2-stage, [b][c][len] layout) ----------------
__global__ void k_bnstat_a(const float* __restrict__ x, float* __restrict__ pst, int len) {
    int c = blockIdx.x, b = blockIdx.y, tid = threadIdx.x;
    const float4* xp = (const float4*)(x + ((size_t)(b * 64 + c)) * len);
    int n4 = len >> 2;
    float s = 0, q = 0;
    for (int i = tid; i < n4; i += 256) {
        float4 v = xp[i];
        s += v.x + v.y + v.z + v.w;
        q += v.x * v.x + v.y * v.y + v.z * v.z + v.w * v.w;
    }
    __shared__ float rs[256], rq[256];
    rs[tid] = s; rq[tid] = q; __syncthreads();
    for (int off = 128; off > 0; off >>= 1) {
        if (tid < off) { rs[tid] += rs[tid + off]; rq[tid] += rq[tid + off]; }
        __syncthreads();
    }
    if (tid == 0) {
        pst[(c * gridDim.y + b) * 2] = rs[0];
        pst[(c * gridDim.y + b) * 2 + 1] = rq[0];
    }
}

__global__ void k_bnfin(const float* __restrict__ pst, const float* __restrict__ g,
                        const float* __restrict__ be, float* __restrict__ stats,
                        int nb, float invcnt) {
    int c = threadIdx.x;
    float s = 0, q = 0;
    for (int b = 0; b < nb; b++) {
        s += pst[(c * nb + b) * 2];
        q += pst[(c * nb + b) * 2 + 1];
    }
    float mean = s * invcnt;
    float var = q * invcnt - mean * mean;
    float sc = g[c] * rsqrtf(var + 1e-4f);
    stats[2 * c] = sc;
    stats[2 * c + 1] = be[c] - mean * sc;
}

__global__ void k_bn_act(const float* __restrict__ x, const float* __restrict__ stats,
                         float* __restrict__ out, int shift, float slope) {
    size_t i = (size_t)blockIdx.x * 256 + threadIdx.x;
    int c = (int)((i >> shift) & 63);
    float sc = stats[2 * c], sh = stats[2 * c + 1];
    float4 v = ((const float4*)x)[i];
    v.x = v.x * sc + sh; v.y = v.y * sc + sh; v.z = v.z * sc + sh; v.w = v.w * sc + sh;
    v.x = v.x > 0 ? v.x : slope * v.x;
    v.y = v.y > 0 ? v.y : slope * v.y;
    v.z = v.z > 0 ? v.z : slope * v.z;
    v.w = v.w > 0 ? v.w : slope * v.w;
    ((float4*)out)[i] = v;
}

// ---------------- devoxelize, fused BN+lrelu, channel-last gather ----------------
__global__ void k_devox2(const float* __restrict__ gcl, const float* __restrict__ stats,
                         const float* __restrict__ nc, float* __restrict__ out) {
    int b = blockIdx.y;
    int tid = threadIdx.x, p = tid >> 4, q = tid & 15;
    int n = blockIdx.x * 16 + p;
    float x = nc[((size_t)b * 3 + 0) * NN + n];
    float y = nc[((size_t)b * 3 + 1) * NN + n];
    float z = nc[((size_t)b * 3 + 2) * NN + n];
    float fx = floorf(x), fy = floorf(y), fz = floorf(z);
    int lx = (int)fx, ly = (int)fy, lz = (int)fz;
    int hx = min(lx + 1, RR - 1), hy = min(ly + 1, RR - 1), hz = min(lz + 1, RR - 1);
    float frx = x - fx, fry = y - fy, frz = z - fz;
    int xx[2] = {lx, hx}, yy[2] = {ly, hy}, zz[2] = {lz, hz};
    float wx[2] = {1.0f - frx, frx}, wy[2] = {1.0f - fry, fry}, wz[2] = {1.0f - frz, frz};
    float sc[4], sh[4];
    #pragma unroll
    for (int j = 0; j < 4; j++) {
        sc[j] = stats[2 * (q * 4 + j)];
        sh[j] = stats[2 * (q * 4 + j) + 1];
    }
    float a0 = 0, a1 = 0, a2 = 0, a3 = 0;
    #pragma unroll
    for (int dx = 0; dx < 2; dx++)
        #pragma unroll
        for (int dy = 0; dy < 2; dy++)
            #pragma unroll
            for (int dz = 0; dz < 2; dz++) {
                int idx = (xx[dx] * RR + yy[dy]) * RR + zz[dz];
                float wt = wx[dx] * wy[dy] * wz[dz];
                float4 v = *(const float4*)&gcl[((size_t)b * R3 + idx) * 64 + q * 4];
                float u0 = v.x * sc[0] + sh[0]; u0 = u0 > 0 ? u0 : 0.1f * u0;
                float u1 = v.y * sc[1] + sh[1]; u1 = u1 > 0 ? u1 : 0.1f * u1;
                float u2 = v.z * sc[2] + sh[2]; u2 = u2 > 0 ? u2 : 0.1f * u2;
                float u3 = v.w * sc[3] + sh[3]; u3 = u3 > 0 ? u3 : 0.1f * u3;
                a0 += wt * u0; a1 += wt * u1; a2 += wt * u2; a3 += wt * u3;
            }
    out[((size_t)(b * 64 + q * 4 + 0)) * NN + n] = a0;
    out[((size_t)(b * 64 + q * 4 + 1)) * NN + n] = a1;
    out[((size_t)(b * 64 + q * 4 + 2)) * NN + n] = a2;
    out[((size_t)(b * 64 + q * 4 + 3)) * NN + n] = a3;
}

// ---------------- fuzzy attention (MFMA) ----------------
__global__ __launch_bounds__(256) void k_fuzzym(const float* __restrict__ coords,
                                                const ushort_t* __restrict__ featb,
                                                float* __restrict__ pnum,
                                                float* __restrict__ pden) {
    __shared__ float cm[3][2048];
    int b = blockIdx.z, mc = blockIdx.y, nt = blockIdx.x;
    int tid = threadIdx.x;
    int w = tid >> 6, lane = tid & 63, l15 = lane & 15, l4 = lane >> 4;
    int m0 = mc * 2048;

    for (int i = tid; i < 2048; i += 256) {
        float a0 = coords[((size_t)b * 3 + 0) * NN + m0 + i];
        float a1 = coords[((size_t)b * 3 + 1) * NN + m0 + i];
        float a2 = coords[((size_t)b * 3 + 2) * NN + m0 + i];
        float inv = 1.0f / fmaxf(sqrtf(a0 * a0 + a1 * a1 + a2 * a2), 1e-12f);
        cm[0][i] = a0 * inv; cm[1][i] = a1 * inv; cm[2][i] = a2 * inv;
    }

    int n = nt * 64 + w * 16 + l15;
    float q0 = coords[((size_t)b * 3 + 0) * NN + n];
    float q1 = coords[((size_t)b * 3 + 1) * NN + n];
    float q2 = coords[((size_t)b * 3 + 2) * NN + n];
    float qi = 10.0f / fmaxf(sqrtf(q0 * q0 + q1 * q1 + q2 * q2), 1e-12f);
    q0 *= qi; q1 *= qi; q2 *= qi;

    const ushort_t* fb = featb + (size_t)b * 64 * NN + m0;
    v4f acc[4];
    #pragma unroll
    for (int cb = 0; cb < 4; cb++) acc[cb] = (v4f){0.0f, 0.0f, 0.0f, 0.0f};
    float den = 0.0f;

    __syncthreads();
    for (int t = 0; t < 64; t++) {
        int mo = t * 32 + l4 * 8;
        float e[8];
        #pragma unroll
        for (int jj = 0; jj < 2; jj++) {
            float4 x0 = *(const float4*)&cm[0][mo + jj * 4];
            float4 x1 = *(const float4*)&cm[1][mo + jj * 4];
            float4 x2 = *(const float4*)&cm[2][mo + jj * 4];
            e[jj * 4 + 0] = __expf(q0 * x0.x + q1 * x1.x + q2 * x2.x);
            e[jj * 4 + 1] = __expf(q0 * x0.y + q1 * x1.y + q2 * x2.y);
            e[jj * 4 + 2] = __expf(q0 * x0.z + q1 * x1.z + q2 * x2.z);
            e[jj * 4 + 3] = __expf(q0 * x0.w + q1 * x1.w + q2 * x2.w);
        }
        den += ((e[0] + e[1]) + (e[2] + e[3])) + ((e[4] + e[5]) + (e[6] + e[7]));
        union { __hip_bfloat162 h[4]; v8s v; } pk;
        pk.h[0] = __float22bfloat162_rn(make_float2(e[0], e[1]));
        pk.h[1] = __float22bfloat162_rn(make_float2(e[2], e[3]));
        pk.h[2] = __float22bfloat162_rn(make_float2(e[4], e[5]));
        pk.h[3] = __float22bfloat162_rn(make_float2(e[6], e[7]));
        #pragma unroll
        for (int cb = 0; cb < 4; cb++) {
            v8s A = *(const v8s*)(fb + (size_t)(cb * 16 + l15) * NN + mo);
            acc[cb] = __builtin_amdgcn_mfma_f32_16x16x32_bf16(A, pk.v, acc[cb], 0, 0, 0);
        }
    }

    den += __shfl_xor(den, 16);
    den += __shfl_xor(den, 32);

    size_t obase = ((size_t)(b * 2 + mc)) * 64 * NN;
    #pragma unroll
    for (int cb = 0; cb < 4; cb++)
        #pragma unroll
        for (int r = 0; r < 4; r++)
            pnum[obase + (size_t)(cb * 16 + l4 * 4 + r) * NN + n] = acc[cb][r];
    if (l4 == 0) pden[((size_t)(b * 2 + mc)) * NN + n] = den;
}

__global__ void k_combine2(const float* __restrict__ pnum, const float* __restrict__ pden,
                           float* __restrict__ fzf) {
    int i = blockIdx.x * 256 + threadIdx.x;  // B*64*NN
    int b = i >> 18, c = (i >> 12) & 63, n = i & 4095;
    float num = pnum[((size_t)(b * 2 + 0) * 64 + c) * NN + n] +
                pnum[((size_t)(b * 2 + 1) * 64 + c) * NN + n];
    float den = pden[((size_t)(b * 2 + 0)) * NN + n] +
                pden[((size_t)(b * 2 + 1)) * NN + n];
    fzf[((size_t)(b * 64 + c)) * NN + n] = num / den;
}

// ---------------- 1x1 conv ----------------
template <int NSEG>
__global__ __launch_bounds__(256) void k_1x1(const float* __restrict__ inA,
                                             const float* __restrict__ inB,
                                             const float* __restrict__ inC,
                                             const float* __restrict__ w,
                                             const float* __restrict__ bias,
                                             float* __restrict__ out) {
    __shared__ float lw[NSEG * 64 * 16];
    int b = blockIdx.z, ob = blockIdx.y;
    int n = blockIdx.x * 64 + (threadIdx.x & 63);
    int og = threadIdx.x >> 6;
    const int CI3 = NSEG * 64;
    for (int i = threadIdx.x; i < CI3 * 16; i += 256) {
        int c = i >> 4, o = i & 15;
        lw[c * 16 + o] = w[(size_t)(ob * 16 + o) * CI3 + c];
    }
    __syncthreads();
    float acc[4] = {0, 0, 0, 0};
    const float* segs[3] = {inA, inB, inC};
    #pragma unroll
    for (int sg = 0; sg < NSEG; sg++) {
        const float* src = segs[sg] + (size_t)b * 64 * NN + n;
        #pragma unroll 8
        for (int c = 0; c < 64; c++) {
            float x = src[(size_t)c * NN];
            float4 wv = *(const float4*)&lw[(sg * 64 + c) * 16 + og * 4];
            acc[0] += x * wv.x; acc[1] += x * wv.y;
            acc[2] += x * wv.z; acc[3] += x * wv.w;
        }
    }
    #pragma unroll
    for (int j = 0; j < 4; j++)
        out[((size_t)(b * 64 + ob * 16 + og * 4 + j)) * NN + n] = acc[j] + bias[ob * 16 + og * 4 + j];
}

// ---------------- launcher ----------------
extern "C" void kernel_launch(void* const* d_in, const int* in_sizes, int n_in,
                              void* d_out, int out_size, void* d_ws, size_t ws_size,
                              hipStream_t stream) {
    const float* features = (const float*)d_in[0];
    const float* coords = (const float*)d_in[1];
    const float* w1 = (const float*)d_in[2];
    // b1 (d_in[3]) skipped: cancelled exactly by BN1 mean subtraction
    const float* g1 = (const float*)d_in[4];
    const float* be1 = (const float*)d_in[5];
    const float* w2 = (const float*)d_in[6];
    // b2 (d_in[7]) skipped: cancelled by BN2
    const float* g2 = (const float*)d_in[8];
    const float* be2 = (const float*)d_in[9];
    const float* wp = (const float*)d_in[10];
    const float* bp = (const float*)d_in[11];
    const float* gp = (const float*)d_in[12];
    const float* bep = (const float*)d_in[13];
    const float* wf = (const float*)d_in[14];
    const float* bf = (const float*)d_in[15];
    const float* wfu = (const float*)d_in[16];
    const float* bfu = (const float*)d_in[17];
    const float* gfu = (const float*)d_in[18];
    const float* befu = (const float*)d_in[19];

    float* ws = (float*)d_ws;
    float* nc = ws;                        // 49152
    int* vidx = (int*)(ws + 49152);        // 16384 (pst overlays after scatter)
    float* pst = ws + 49152;               // 16384 floats (nb<=128 partials)
    float* cnt = ws + 65536;               // 131072 (pden overlays after k_avg2)
    float* pden = cnt;
    float* gridCL = ws + 196608;           // 8388608 f32 channel-last grid
    float* gTpool = ws + 8585216;          // 8388608 floats: gT bf16 / pnum later
    ushort_t* gT = (ushort_t*)gTpool;
    float* pnum = gTpool;
    float* stats = ws + 16973824;          // 512
    float* voxreg = ws + 16974336;         // 1048576 (wB1/wB2 live here until devox)
    ushort_t* wB1 = (ushort_t*)voxreg;
    ushort_t* wB2 = wB1 + 110592;
    float* vox = voxreg;
    float* pt = ws + 18022912;
    float* fzf = ws + 19071488;
    float* fzc = ws + 20120064;
    float* fpre = ws + 21168640;           // featb overlays (consumed before fusion)
    ushort_t* featb = (ushort_t*)fpre;

    float* out = (float*)d_out;

    hipMemsetAsync(cnt, 0, (size_t)(131072 + 8388608) * 4, stream);

    // prep
    k_f2b<<<BB * 64 * NN / 8 / 256, 256, 0, stream>>>(features, featb);
    k_twb<<<432, 256, 0, stream>>>(w1, wB1);
    k_twb<<<432, 256, 0, stream>>>(w2, wB2);
    k_nc<<<BB, 256, 0, stream>>>(coords, nc, vidx);
    k_scatter<<<BB * NN / 64, 256, 0, stream>>>(features, vidx, gridCL, cnt);
    k_avg2<<<BB * R3 * 64 / 8 / 256, 256, 0, stream>>>(gridCL, cnt, gT);

    // voxel branch (MFMA convs, channel-last)
    k_convm<<<1024, 256, 0, stream>>>(gT, wB1, gridCL);
    k_bnstat_cl<<<dim3(32, BB), 256, 0, stream>>>(gridCL, pst);
    k_bnfin<<<1, 64, 0, stream>>>(pst, g1, be1, stats, 128, 1.0f / (BB * R3));
    k_bncast<<<BB * R3 * 64 / 8 / 256, 256, 0, stream>>>(gridCL, stats, 0.1f, gT);
    k_convm<<<1024, 256, 0, stream>>>(gT, wB2, gridCL);
    k_bnstat_cl<<<dim3(32, BB), 256, 0, stream>>>(gridCL, pst);
    k_bnfin<<<1, 64, 0, stream>>>(pst, g2, be2, stats + 128, 128, 1.0f / (BB * R3));
    k_devox2<<<dim3(NN / 16, BB), 256, 0, stream>>>(gridCL, stats + 128, nc, vox);

    // fuzzy branch (pnum overlays gT region — gT dead after conv2)
    k_fuzzym<<<dim3(64, 2, BB), 256, 0, stream>>>(coords, featb, pnum, pden);
    k_combine2<<<BB * 64 * NN / 256, 256, 0, stream>>>(pnum, pden, fzf);

    // point branch
    k_1x1<1><<<dim3(NN / 64, 4, BB), 256, 0, stream>>>(features, nullptr, nullptr, wp, bp, pt);
    k_bnstat_a<<<dim3(64, BB), 256, 0, stream>>>(pt, pst, NN);
    k_bnfin<<<1, 64, 0, stream>>>(pst, gp, bep, stats + 256, BB, 1.0f / (BB * NN));
    k_bn_act<<<BB * 64 * NN / 4 / 256, 256, 0, stream>>>(pt, stats + 256, pt, 10, 0.0f);

    // fuzzy proj
    k_1x1<1><<<dim3(NN / 64, 4, BB), 256, 0, stream>>>(fzf, nullptr, nullptr, wf, bf, fzc);

    // fusion
    k_1x1<3><<<dim3(NN / 64, 4, BB), 256, 0, stream>>>(vox, pt, fzc, wfu, bfu, fpre);
    k_bnstat_a<<<dim3(64, BB), 256, 0, stream>>>(fpre, pst, NN);
    k_bnfin<<<1, 64, 0, stream>>>(pst, gfu, befu, stats + 384, BB, 1.0f / (BB * NN));
    k_bn_act<<<BB * 64 * NN / 4 / 256, 256, 0, stream>>>(fpre, stats + 384, out, 10, 0.0f);

    hipMemcpyAsync(out + (size_t)BB * CO * NN, coords, (size_t)BB * 3 * NN * 4,
                   hipMemcpyDeviceToDevice, stream);
}

// Round 6
// 439.689 us; speedup vs baseline: 1.5497x; 1.5497x over previous
//
#include <hip/hip_runtime.h>
#include <hip/hip_bf16.h>
#include <math.h>

#define RR 32
#define R3 32768
#define BB 4
#define CI 64
#define CO 64
#define NN 4096

typedef short v8s __attribute__((ext_vector_type(8)));
typedef float v4f __attribute__((ext_vector_type(4)));
typedef unsigned short ushort_t;

__device__ __forceinline__ unsigned short f2bf(float f) {
    unsigned int u = __float_as_uint(f);
    unsigned int r = (u + 0x7FFFu + ((u >> 16) & 1u)) >> 16;
    return (unsigned short)r;
}

__device__ __forceinline__ void gll16(const void* g, void* l) {
    __builtin_amdgcn_global_load_lds((const __attribute__((address_space(1))) unsigned int*)g,
                                     (__attribute__((address_space(3))) unsigned int*)l, 16, 0, 0);
}

// ---------------- block reduce helpers ----------------
__device__ __forceinline__ float blockReduceSum(float v, float* sm) {
    int tid = threadIdx.x;
    sm[tid] = v; __syncthreads();
    for (int off = 128; off > 0; off >>= 1) {
        if (tid < off) sm[tid] += sm[tid + off];
        __syncthreads();
    }
    float r = sm[0]; __syncthreads();
    return r;
}
__device__ __forceinline__ float blockReduceMax(float v, float* sm) {
    int tid = threadIdx.x;
    sm[tid] = v; __syncthreads();
    for (int off = 128; off > 0; off >>= 1) {
        if (tid < off) sm[tid] = fmaxf(sm[tid], sm[tid + off]);
        __syncthreads();
    }
    float r = sm[0]; __syncthreads();
    return r;
}

// ---------------- voxel coords ----------------
__global__ void k_nc(const float* __restrict__ coords, float* __restrict__ nc,
                     int* __restrict__ vidx) {
    int b = blockIdx.x, tid = threadIdx.x;
    __shared__ float sm[256];
    const float* cb = coords + (size_t)b * 3 * NN;
    float s0 = 0, s1 = 0, s2 = 0;
    for (int n = tid; n < NN; n += 256) {
        s0 += cb[n]; s1 += cb[NN + n]; s2 += cb[2 * NN + n];
    }
    float m0 = blockReduceSum(s0, sm) * (1.0f / NN);
    float m1 = blockReduceSum(s1, sm) * (1.0f / NN);
    float m2 = blockReduceSum(s2, sm) * (1.0f / NN);
    float mx = 0;
    for (int n = tid; n < NN; n += 256) {
        float dx = cb[n] - m0, dy = cb[NN + n] - m1, dz = cb[2 * NN + n] - m2;
        mx = fmaxf(mx, dx * dx + dy * dy + dz * dz);
    }
    mx = blockReduceMax(mx, sm);
    float denom = 2.0f * sqrtf(mx);
    float mean[3] = {m0, m1, m2};
    for (int n = tid; n < NN; n += 256) {
        int vi[3];
        #pragma unroll
        for (int ax = 0; ax < 3; ax++) {
            float x = (cb[ax * NN + n] - mean[ax]) / denom + 0.5f;
            x = x * RR;
            x = fminf(fmaxf(x, 0.0f), (float)(RR - 1));
            nc[((size_t)b * 3 + ax) * NN + n] = x;
            vi[ax] = (int)rintf(x);
        }
        vidx[b * NN + n] = (vi[0] * RR + vi[1]) * RR + vi[2];
    }
}

// ---------------- scatter-mean (channel-first, atomics spread across planes) ----------------
__global__ void k_scatter(const float* __restrict__ feat, const int* __restrict__ vidx,
                          float* __restrict__ grid, float* __restrict__ cnt) {
    int tid = threadIdx.x;
    int pid = blockIdx.x * 64 + (tid & 63);
    int cg = tid >> 6;
    int b = pid / NN, n = pid % NN;
    int idx = vidx[pid];
    if (cg == 0) atomicAdd(&cnt[b * R3 + idx], 1.0f);
    #pragma unroll 4
    for (int c = cg * 16; c < cg * 16 + 16; c++)
        atomicAdd(&grid[((size_t)(b * CI + c)) * R3 + idx], feat[((size_t)(b * CI + c)) * NN + n]);
}

// ---------------- divide + transpose + bf16 cast: cf f32 -> cl bf16 ----------------
__global__ void k_avgT(const float* __restrict__ grid, const float* __restrict__ cnt,
                       ushort_t* __restrict__ gT) {
    __shared__ float ld[64][65];
    int b = blockIdx.y, s0 = blockIdx.x * 64, tid = threadIdx.x;
    int sl = tid & 63, cq = tid >> 6;
    const float* xb = grid + (size_t)b * 64 * R3;
    #pragma unroll
    for (int k = 0; k < 16; k++) {
        int c = cq * 16 + k;
        ld[sl][c] = xb[(size_t)c * R3 + s0 + sl];
    }
    __syncthreads();
    int v = tid >> 2, q = tid & 3;
    float inv = 1.0f / fmaxf(cnt[b * R3 + s0 + v], 1.0f);
    unsigned int pk[8];
    #pragma unroll
    for (int j = 0; j < 8; j++) {
        int c = q * 16 + j * 2;
        float a = ld[v][c] * inv, d = ld[v][c + 1] * inv;
        pk[j] = (unsigned int)f2bf(a) | ((unsigned int)f2bf(d) << 16);
    }
    uint4* op = (uint4*)(gT + ((size_t)(b * R3 + s0 + v)) * 64 + q * 16);
    op[0] = make_uint4(pk[0], pk[1], pk[2], pk[3]);
    op[1] = make_uint4(pk[4], pk[5], pk[6], pk[7]);
}

// ---------------- features f32 -> bf16 ----------------
__global__ void k_f2b(const float* __restrict__ x, ushort_t* __restrict__ o) {
    size_t i = (size_t)blockIdx.x * 256 + threadIdx.x;
    float4 a = ((const float4*)x)[i * 2];
    float4 b = ((const float4*)x)[i * 2 + 1];
    union { __hip_bfloat162 h[4]; uint4 u; } pk;
    pk.h[0] = __float22bfloat162_rn(make_float2(a.x, a.y));
    pk.h[1] = __float22bfloat162_rn(make_float2(a.z, a.w));
    pk.h[2] = __float22bfloat162_rn(make_float2(b.x, b.y));
    pk.h[3] = __float22bfloat162_rn(make_float2(b.z, b.w));
    ((uint4*)o)[i] = pk.u;
}

// ---------------- weight transform: wS[dzdy 9][cih 2][dx 3][co 64][cis 32] bf16 ----------------
__global__ void k_tws(const float* __restrict__ w, ushort_t* __restrict__ wS) {
    int i = blockIdx.x * 256 + threadIdx.x;  // 110592
    int cis = i & 31, co = (i >> 5) & 63;
    int dx = (i >> 11) % 3, cih = (i / 6144) & 1, dzdy = i / 12288;
    int k = dzdy * 3 + dx, ci = cih * 32 + cis;
    wS[i] = f2bf(w[((size_t)co * CI + ci) * 27 + k]);
}

// ---------------- BN + lrelu + bf16 cast (cl -> cl) ----------------
__global__ void k_bncast(const float* __restrict__ x, const float* __restrict__ stats,
                         float slope, ushort_t* __restrict__ o) {
    size_t i = (size_t)blockIdx.x * 256 + threadIdx.x;  // over B*R3*64/8
    int c0 = (int)((i * 8) & 63);
    float4 a = ((const float4*)x)[i * 2];
    float4 d = ((const float4*)x)[i * 2 + 1];
    float va[8] = {a.x, a.y, a.z, a.w, d.x, d.y, d.z, d.w};
    unsigned pk[4];
    #pragma unroll
    for (int j = 0; j < 4; j++) {
        float u0 = va[2 * j] * stats[2 * (c0 + 2 * j)] + stats[2 * (c0 + 2 * j) + 1];
        float u1 = va[2 * j + 1] * stats[2 * (c0 + 2 * j) + 2] + stats[2 * (c0 + 2 * j) + 3];
        u0 = u0 > 0 ? u0 : slope * u0;
        u1 = u1 > 0 ? u1 : slope * u1;
        pk[j] = (unsigned)f2bf(u0) | ((unsigned)f2bf(u1) << 16);
    }
    ((uint4*)o)[i] = make_uint4(pk[0], pk[1], pk[2], pk[3]);
}

// ---------------- LDS-staged MFMA conv3d 3x3x3 ----------------
// gT: bf16 cl [b][z][y][x][ci]; wS: bf16 [9][2][3][64][32]; outCL: f32 [b][vox][co]
// 512 blocks (yt4, z32, b4; XCD-swizzled), 4 waves, 64KB LDS (input plane 40KB + 2x12KB weights)
__global__ __launch_bounds__(256) void k_convlds(const ushort_t* __restrict__ gT,
                                                 const ushort_t* __restrict__ wS,
                                                 float* __restrict__ outCL) {
    __shared__ ushort_t lin[20480];     // 40960B: 10 rows x 32 x x 64 ci (granule-swizzled)
    __shared__ ushort_t lw[2][6144];    // 2 x 12288B: [dx3][co64][cis32]
    int bid = blockIdx.x;
    int wgid = (bid & 7) * 64 + (bid >> 3);
    int yt = wgid & 3, z0 = (wgid >> 2) & 31, b = wgid >> 7;
    int tid = threadIdx.x;
    int w = __builtin_amdgcn_readfirstlane(tid >> 6);
    int lane = tid & 63, l15 = lane & 15, l4 = lane >> 4;
    int y0 = yt * 8;
    const ushort_t* gTb = gT + (size_t)b * R3 * 64;

    // per-frag per-lane voxel base (row local 0..9 = w*2+(f>>1)+dy; x = (f&1)*16+l15+dx-1)
    int voxF[4];
    #pragma unroll
    for (int f = 0; f < 4; f++)
        voxF[f] = (w * 2 + (f >> 1)) * 32 + (f & 1) * 16 + l15 - 1;
    bool xlo_ok = (l15 != 0), xhi_ok = (l15 != 15);

    const v8s vzero = {};
    v4f acc[4][4];
    #pragma unroll
    for (int m = 0; m < 4; m++)
        #pragma unroll
        for (int f = 0; f < 4; f++)
            acc[m][f] = (v4f){0.0f, 0.0f, 0.0f, 0.0f};

    // ---- weight stage s -> lw[s&1]: 3 chunks/wave of 256 granules ----
#define WSTAGE(s)                                                              \
    do {                                                                       \
        const ushort_t* _src = wS + (size_t)(s) * 6144;                        \
        ushort_t* _dst = lw[(s) & 1];                                          \
        _Pragma("unroll") for (int _i = 0; _i < 3; _i++) {                     \
            int _p = _i * 256 + w * 64;                                        \
            gll16(_src + (size_t)(_p + lane) * 8, _dst + (size_t)_p * 8);      \
        }                                                                      \
    } while (0)

    // ---- input stage for dz: zero-fill invalid, swizzled gll otherwise ----
#define ISTAGE(dz)                                                             \
    do {                                                                       \
        int _zp = z0 - 1 + (dz);                                               \
        if (_zp < 0 || _zp > 31) {                                             \
            for (int _q = 0; _q < 10; _q++)                                    \
                *(v8s*)&lin[(size_t)(w * 640 + _q * 64 + lane) * 8] = vzero;   \
        } else {                                                               \
            if (yt == 0) *(v8s*)&lin[(size_t)tid * 8] = vzero;                 \
            if (yt == 3) *(v8s*)&lin[(size_t)(2304 + tid) * 8] = vzero;        \
            const ushort_t* _pb = gTb + ((size_t)_zp * 1024 + (size_t)(y0 - 1) * 32) * 64; \
            int _g0 = (yt == 0) ? 256 : 0;                                     \
            int _nc = 10 - (yt == 0) - (yt == 3);                              \
            for (int _i = 0; _i < _nc; _i++) {                                 \
                int _pbase = _g0 + _i * 256 + w * 64;                          \
                int _p = _pbase + lane;                                        \
                int _vx = _p >> 3, _js = _p & 7;                               \
                int _sg = _vx * 8 + (_js ^ (_vx & 7));                         \
                gll16(_pb + (size_t)_sg * 8, lin + (size_t)_pbase * 8);        \
            }                                                                  \
        }                                                                      \
    } while (0)

    WSTAGE(0);
    for (int s = 0; s < 18; s++) {
        int dz = s / 6, dy = (s / 2) % 3, cih = s & 1;
        (void)dz;
        asm volatile("s_barrier" ::: "memory");           // prev compute done -> buffers free
        if ((s % 6) == 0) ISTAGE(s / 6);
        if (s + 1 < 18) WSTAGE(s + 1);
        if (s + 1 < 18) asm volatile("s_waitcnt vmcnt(3) lgkmcnt(0)" ::: "memory");
        else            asm volatile("s_waitcnt vmcnt(0) lgkmcnt(0)" ::: "memory");
        asm volatile("s_barrier" ::: "memory");           // stage(s) data visible

        const ushort_t* lwb = lw[s & 1];
        #pragma unroll
        for (int dx = 0; dx < 3; dx++) {
            v8s Bf[4];
            #pragma unroll
            for (int f = 0; f < 4; f++) {
                int vox = voxF[f] + dy * 32 + dx;
                int g = vox * 8 + ((cih * 4 + l4) ^ (vox & 7));
                int bix = g * 16;
                bix = bix < 0 ? 0 : bix;
                v8s vb = *(const v8s*)((const char*)lin + bix);
                bool ok = (dx == 0 && (f & 1) == 0) ? xlo_ok :
                          (dx == 2 && (f & 1) == 1) ? xhi_ok : true;
                Bf[f] = ok ? vb : vzero;
            }
            const ushort_t* ap = lwb + dx * 2048 + l15 * 32 + l4 * 8;
            #pragma unroll
            for (int m = 0; m < 4; m++) {
                v8s Af = *(const v8s*)(ap + m * 512);
                #pragma unroll
                for (int f = 0; f < 4; f++)
                    acc[m][f] = __builtin_amdgcn_mfma_f32_16x16x32_bf16(Af, Bf[f], acc[m][f], 0, 0, 0);
            }
        }
    }

    // channel-last f4 stores: co = m*16 + l4*4 + r
    #pragma unroll
    for (int m = 0; m < 4; m++) {
        #pragma unroll
        for (int f = 0; f < 4; f++) {
            int y = y0 + w * 2 + (f >> 1);
            int x = (f & 1) * 16 + l15;
            float4 o = make_float4(acc[m][f][0], acc[m][f][1], acc[m][f][2], acc[m][f][3]);
            *(float4*)&outCL[((size_t)b * R3 + z0 * 1024 + y * 32 + x) * 64 + m * 16 + l4 * 4] = o;
        }
    }
#undef WSTAGE
#undef ISTAGE
}

// ---------------- BN stats, channel-last ----------------
__global__ void k_bnstat_cl(const float* __restrict__ x, float* __restrict__ pst) {
    int slab = blockIdx.x, b = blockIdx.y, tid = threadIdx.x;
    int c = tid & 63, r = tid >> 6;
    const float* xb = x + ((size_t)b * R3 + slab * 1024) * 64;
    float s = 0, q = 0;
    for (int i = r; i < 1024; i += 4) {
        float v = xb[(size_t)i * 64 + c];
        s += v; q += v * v;
    }
    __shared__ float rs[256], rq[256];
    rs[tid] = s; rq[tid] = q; __syncthreads();
    if (tid < 64) {
        s = rs[tid] + rs[tid + 64] + rs[tid + 128] + rs[tid + 192];
        q = rq[tid] + rq[tid + 64] + rq[tid + 128] + rq[tid + 192];
        int j = b * 32 + slab;
        pst[(tid * 128 + j) * 2] = s;
        pst[(tid * 128 + j) * 2 + 1] = q;
    }
}

// ---------------- BN stats ([b][c][len]) ----------------
__global__ void k_bnstat_a(const float* __restrict__ x, float* __restrict__ pst, int len) {
    int c = blockIdx.x, b = blockIdx.y, tid = threadIdx.x;
    const float4* xp = (const float4*)(x + ((size_t)(b * 64 + c)) * len);
    int n4 = len >> 2;
    float s = 0, q = 0;
    for (int i = tid; i < n4; i += 256) {
        float4 v = xp[i];
        s += v.x + v.y + v.z + v.w;
        q += v.x * v.x + v.y * v.y + v.z * v.z + v.w * v.w;
    }
    __shared__ float rs[256], rq[256];
    rs[tid] = s; rq[tid] = q; __syncthreads();
    for (int off = 128; off > 0; off >>= 1) {
        if (tid < off) { rs[tid] += rs[tid + off]; rq[tid] += rq[tid + off]; }
        __syncthreads();
    }
    if (tid == 0) {
        pst[(c * gridDim.y + b) * 2] = rs[0];
        pst[(c * gridDim.y + b) * 2 + 1] = rq[0];
    }
}

__global__ void k_bnfin(const float* __restrict__ pst, const float* __restrict__ g,
                        const float* __restrict__ be, float* __restrict__ stats,
                        int nb, float invcnt) {
    int c = threadIdx.x;
    float s = 0, q = 0;
    for (int b = 0; b < nb; b++) {
        s += pst[(c * nb + b) * 2];
        q += pst[(c * nb + b) * 2 + 1];
    }
    float mean = s * invcnt;
    float var = q * invcnt - mean * mean;
    float sc = g[c] * rsqrtf(var + 1e-4f);
    stats[2 * c] = sc;
    stats[2 * c + 1] = be[c] - mean * sc;
}

__global__ void k_bn_act(const float* __restrict__ x, const float* __restrict__ stats,
                         float* __restrict__ out, int shift, float slope) {
    size_t i = (size_t)blockIdx.x * 256 + threadIdx.x;
    int c = (int)((i >> shift) & 63);
    float sc = stats[2 * c], sh = stats[2 * c + 1];
    float4 v = ((const float4*)x)[i];
    v.x = v.x * sc + sh; v.y = v.y * sc + sh; v.z = v.z * sc + sh; v.w = v.w * sc + sh;
    v.x = v.x > 0 ? v.x : slope * v.x;
    v.y = v.y > 0 ? v.y : slope * v.y;
    v.z = v.z > 0 ? v.z : slope * v.z;
    v.w = v.w > 0 ? v.w : slope * v.w;
    ((float4*)out)[i] = v;
}

// ---------------- devoxelize, fused BN+lrelu, channel-last gather ----------------
__global__ void k_devox2(const float* __restrict__ gcl, const float* __restrict__ stats,
                         const float* __restrict__ nc, float* __restrict__ out) {
    int b = blockIdx.y;
    int tid = threadIdx.x, p = tid >> 4, q = tid & 15;
    int n = blockIdx.x * 16 + p;
    float x = nc[((size_t)b * 3 + 0) * NN + n];
    float y = nc[((size_t)b * 3 + 1) * NN + n];
    float z = nc[((size_t)b * 3 + 2) * NN + n];
    float fx = floorf(x), fy = floorf(y), fz = floorf(z);
    int lx = (int)fx, ly = (int)fy, lz = (int)fz;
    int hx = min(lx + 1, RR - 1), hy = min(ly + 1, RR - 1), hz = min(lz + 1, RR - 1);
    float frx = x - fx, fry = y - fy, frz = z - fz;
    int xx[2] = {lx, hx}, yy[2] = {ly, hy}, zz[2] = {lz, hz};
    float wx[2] = {1.0f - frx, frx}, wy[2] = {1.0f - fry, fry}, wz[2] = {1.0f - frz, frz};
    float sc[4], sh[4];
    #pragma unroll
    for (int j = 0; j < 4; j++) {
        sc[j] = stats[2 * (q * 4 + j)];
        sh[j] = stats[2 * (q * 4 + j) + 1];
    }
    float a0 = 0, a1 = 0, a2 = 0, a3 = 0;
    #pragma unroll
    for (int dx = 0; dx < 2; dx++)
        #pragma unroll
        for (int dy = 0; dy < 2; dy++)
            #pragma unroll
            for (int dz = 0; dz < 2; dz++) {
                int idx = (xx[dx] * RR + yy[dy]) * RR + zz[dz];
                float wt = wx[dx] * wy[dy] * wz[dz];
                float4 v = *(const float4*)&gcl[((size_t)b * R3 + idx) * 64 + q * 4];
                float u0 = v.x * sc[0] + sh[0]; u0 = u0 > 0 ? u0 : 0.1f * u0;
                float u1 = v.y * sc[1] + sh[1]; u1 = u1 > 0 ? u1 : 0.1f * u1;
                float u2 = v.z * sc[2] + sh[2]; u2 = u2 > 0 ? u2 : 0.1f * u2;
                float u3 = v.w * sc[3] + sh[3]; u3 = u3 > 0 ? u3 : 0.1f * u3;
                a0 += wt * u0; a1 += wt * u1; a2 += wt * u2; a3 += wt * u3;
            }
    out[((size_t)(b * 64 + q * 4 + 0)) * NN + n] = a0;
    out[((size_t)(b * 64 + q * 4 + 1)) * NN + n] = a1;
    out[((size_t)(b * 64 + q * 4 + 2)) * NN + n] = a2;
    out[((size_t)(b * 64 + q * 4 + 3)) * NN + n] = a3;
}

// ---------------- fuzzy attention (MFMA) ----------------
__global__ __launch_bounds__(256) void k_fuzzym(const float* __restrict__ coords,
                                                const ushort_t* __restrict__ featb,
                                                float* __restrict__ pnum,
                                                float* __restrict__ pden) {
    __shared__ float cm[3][2048];
    int b = blockIdx.z, mc = blockIdx.y, nt = blockIdx.x;
    int tid = threadIdx.x;
    int w = tid >> 6, lane = tid & 63, l15 = lane & 15, l4 = lane >> 4;
    int m0 = mc * 2048;

    for (int i = tid; i < 2048; i += 256) {
        float a0 = coords[((size_t)b * 3 + 0) * NN + m0 + i];
        float a1 = coords[((size_t)b * 3 + 1) * NN + m0 + i];
        float a2 = coords[((size_t)b * 3 + 2) * NN + m0 + i];
        float inv = 1.0f / fmaxf(sqrtf(a0 * a0 + a1 * a1 + a2 * a2), 1e-12f);
        cm[0][i] = a0 * inv; cm[1][i] = a1 * inv; cm[2][i] = a2 * inv;
    }

    int n = nt * 64 + w * 16 + l15;
    float q0 = coords[((size_t)b * 3 + 0) * NN + n];
    float q1 = coords[((size_t)b * 3 + 1) * NN + n];
    float q2 = coords[((size_t)b * 3 + 2) * NN + n];
    float qi = 10.0f / fmaxf(sqrtf(q0 * q0 + q1 * q1 + q2 * q2), 1e-12f);
    q0 *= qi; q1 *= qi; q2 *= qi;

    const ushort_t* fb = featb + (size_t)b * 64 * NN + m0;
    v4f acc[4];
    #pragma unroll
    for (int cb = 0; cb < 4; cb++) acc[cb] = (v4f){0.0f, 0.0f, 0.0f, 0.0f};
    float den = 0.0f;

    __syncthreads();
    for (int t = 0; t < 64; t++) {
        int mo = t * 32 + l4 * 8;
        float e[8];
        #pragma unroll
        for (int jj = 0; jj < 2; jj++) {
            float4 x0 = *(const float4*)&cm[0][mo + jj * 4];
            float4 x1 = *(const float4*)&cm[1][mo + jj * 4];
            float4 x2 = *(const float4*)&cm[2][mo + jj * 4];
            e[jj * 4 + 0] = __expf(q0 * x0.x + q1 * x1.x + q2 * x2.x);
            e[jj * 4 + 1] = __expf(q0 * x0.y + q1 * x1.y + q2 * x2.y);
            e[jj * 4 + 2] = __expf(q0 * x0.z + q1 * x1.z + q2 * x2.z);
            e[jj * 4 + 3] = __expf(q0 * x0.w + q1 * x1.w + q2 * x2.w);
        }
        den += ((e[0] + e[1]) + (e[2] + e[3])) + ((e[4] + e[5]) + (e[6] + e[7]));
        union { __hip_bfloat162 h[4]; v8s v; } pk;
        pk.h[0] = __float22bfloat162_rn(make_float2(e[0], e[1]));
        pk.h[1] = __float22bfloat162_rn(make_float2(e[2], e[3]));
        pk.h[2] = __float22bfloat162_rn(make_float2(e[4], e[5]));
        pk.h[3] = __float22bfloat162_rn(make_float2(e[6], e[7]));
        #pragma unroll
        for (int cb = 0; cb < 4; cb++) {
            v8s A = *(const v8s*)(fb + (size_t)(cb * 16 + l15) * NN + mo);
            acc[cb] = __builtin_amdgcn_mfma_f32_16x16x32_bf16(A, pk.v, acc[cb], 0, 0, 0);
        }
    }

    den += __shfl_xor(den, 16);
    den += __shfl_xor(den, 32);

    size_t obase = ((size_t)(b * 2 + mc)) * 64 * NN;
    #pragma unroll
    for (int cb = 0; cb < 4; cb++)
        #pragma unroll
        for (int r = 0; r < 4; r++)
            pnum[obase + (size_t)(cb * 16 + l4 * 4 + r) * NN + n] = acc[cb][r];
    if (l4 == 0) pden[((size_t)(b * 2 + mc)) * NN + n] = den;
}

__global__ void k_combine2(const float* __restrict__ pnum, const float* __restrict__ pden,
                           float* __restrict__ fzf) {
    int i = blockIdx.x * 256 + threadIdx.x;
    int b = i >> 18, c = (i >> 12) & 63, n = i & 4095;
    float num = pnum[((size_t)(b * 2 + 0) * 64 + c) * NN + n] +
                pnum[((size_t)(b * 2 + 1) * 64 + c) * NN + n];
    float den = pden[((size_t)(b * 2 + 0)) * NN + n] +
                pden[((size_t)(b * 2 + 1)) * NN + n];
    fzf[((size_t)(b * 64 + c)) * NN + n] = num / den;
}

// ---------------- 1x1 conv ----------------
template <int NSEG>
__global__ __launch_bounds__(256) void k_1x1(const float* __restrict__ inA,
                                             const float* __restrict__ inB,
                                             const float* __restrict__ inC,
                                             const float* __restrict__ w,
                                             const float* __restrict__ bias,
                                             float* __restrict__ out) {
    __shared__ float lw[NSEG * 64 * 16];
    int b = blockIdx.z, ob = blockIdx.y;
    int n = blockIdx.x * 64 + (threadIdx.x & 63);
    int og = threadIdx.x >> 6;
    const int CI3 = NSEG * 64;
    for (int i = threadIdx.x; i < CI3 * 16; i += 256) {
        int c = i >> 4, o = i & 15;
        lw[c * 16 + o] = w[(size_t)(ob * 16 + o) * CI3 + c];
    }
    __syncthreads();
    float acc[4] = {0, 0, 0, 0};
    const float* segs[3] = {inA, inB, inC};
    #pragma unroll
    for (int sg = 0; sg < NSEG; sg++) {
        const float* src = segs[sg] + (size_t)b * 64 * NN + n;
        #pragma unroll 8
        for (int c = 0; c < 64; c++) {
            float x = src[(size_t)c * NN];
            float4 wv = *(const float4*)&lw[(sg * 64 + c) * 16 + og * 4];
            acc[0] += x * wv.x; acc[1] += x * wv.y;
            acc[2] += x * wv.z; acc[3] += x * wv.w;
        }
    }
    #pragma unroll
    for (int j = 0; j < 4; j++)
        out[((size_t)(b * 64 + ob * 16 + og * 4 + j)) * NN + n] = acc[j] + bias[ob * 16 + og * 4 + j];
}

// ---------------- launcher ----------------
extern "C" void kernel_launch(void* const* d_in, const int* in_sizes, int n_in,
                              void* d_out, int out_size, void* d_ws, size_t ws_size,
                              hipStream_t stream) {
    const float* features = (const float*)d_in[0];
    const float* coords = (const float*)d_in[1];
    const float* w1 = (const float*)d_in[2];
    const float* g1 = (const float*)d_in[4];
    const float* be1 = (const float*)d_in[5];
    const float* w2 = (const float*)d_in[6];
    const float* g2 = (const float*)d_in[8];
    const float* be2 = (const float*)d_in[9];
    const float* wp = (const float*)d_in[10];
    const float* bp = (const float*)d_in[11];
    const float* gp = (const float*)d_in[12];
    const float* bep = (const float*)d_in[13];
    const float* wf = (const float*)d_in[14];
    const float* bf = (const float*)d_in[15];
    const float* wfu = (const float*)d_in[16];
    const float* bfu = (const float*)d_in[17];
    const float* gfu = (const float*)d_in[18];
    const float* befu = (const float*)d_in[19];

    float* ws = (float*)d_ws;
    float* nc = ws;                        // 49152
    int* vidx = (int*)(ws + 49152);        // 16384 (pst overlays after scatter)
    float* pst = ws + 49152;
    float* cnt = ws + 65536;               // 131072 (pden overlays later)
    float* pden = cnt;
    float* gridA = ws + 196608;            // 33.5MB: cf f32 scatter grid, then cl f32 conv out
    float* gridCL = gridA;
    float* gTpool = ws + 8585216;          // 33.5MB: gT bf16 / pnum later
    ushort_t* gT = (ushort_t*)gTpool;
    float* pnum = gTpool;
    float* stats = ws + 16973824;          // 512
    float* voxreg = ws + 16974336;         // wS1/wS2 live here until devox
    ushort_t* wS1 = (ushort_t*)voxreg;     // 110592 ushorts
    ushort_t* wS2 = wS1 + 110592;
    float* vox = voxreg;
    float* pt = ws + 18022912;
    float* fzf = ws + 19071488;
    float* fzc = ws + 20120064;
    float* fpre = ws + 21168640;           // featb overlays (consumed before fusion)
    ushort_t* featb = (ushort_t*)fpre;

    float* out = (float*)d_out;

    hipMemsetAsync(cnt, 0, (size_t)(131072 + 8388608) * 4, stream);

    // prep
    k_f2b<<<BB * 64 * NN / 8 / 256, 256, 0, stream>>>(features, featb);
    k_tws<<<432, 256, 0, stream>>>(w1, wS1);
    k_tws<<<432, 256, 0, stream>>>(w2, wS2);
    k_nc<<<BB, 256, 0, stream>>>(coords, nc, vidx);
    k_scatter<<<BB * NN / 64, 256, 0, stream>>>(features, vidx, gridA, cnt);
    k_avgT<<<dim3(512, BB), 256, 0, stream>>>(gridA, cnt, gT);

    // voxel branch (LDS-staged MFMA convs, channel-last)
    k_convlds<<<512, 256, 0, stream>>>(gT, wS1, gridCL);
    k_bnstat_cl<<<dim3(32, BB), 256, 0, stream>>>(gridCL, pst);
    k_bnfin<<<1, 64, 0, stream>>>(pst, g1, be1, stats, 128, 1.0f / (BB * R3));
    k_bncast<<<BB * R3 * 64 / 8 / 256, 256, 0, stream>>>(gridCL, stats, 0.1f, gT);
    k_convlds<<<512, 256, 0, stream>>>(gT, wS2, gridCL);
    k_bnstat_cl<<<dim3(32, BB), 256, 0, stream>>>(gridCL, pst);
    k_bnfin<<<1, 64, 0, stream>>>(pst, g2, be2, stats + 128, 128, 1.0f / (BB * R3));
    k_devox2<<<dim3(NN / 16, BB), 256, 0, stream>>>(gridCL, stats + 128, nc, vox);

    // fuzzy branch (pnum overlays gT region — gT dead after conv2)
    k_fuzzym<<<dim3(64, 2, BB), 256, 0, stream>>>(coords, featb, pnum, pden);
    k_combine2<<<BB * 64 * NN / 256, 256, 0, stream>>>(pnum, pden, fzf);

    // point branch
    k_1x1<1><<<dim3(NN / 64, 4, BB), 256, 0, stream>>>(features, nullptr, nullptr, wp, bp, pt);
    k_bnstat_a<<<dim3(64, BB), 256, 0, stream>>>(pt, pst, NN);
    k_bnfin<<<1, 64, 0, stream>>>(pst, gp, bep, stats + 256, BB, 1.0f / (BB * NN));
    k_bn_act<<<BB * 64 * NN / 4 / 256, 256, 0, stream>>>(pt, stats + 256, pt, 10, 0.0f);

    // fuzzy proj
    k_1x1<1><<<dim3(NN / 64, 4, BB), 256, 0, stream>>>(fzf, nullptr, nullptr, wf, bf, fzc);

    // fusion
    k_1x1<3><<<dim3(NN / 64, 4, BB), 256, 0, stream>>>(vox, pt, fzc, wfu, bfu, fpre);
    k_bnstat_a<<<dim3(64, BB), 256, 0, stream>>>(fpre, pst, NN);
    k_bnfin<<<1, 64, 0, stream>>>(pst, gfu, befu, stats + 384, BB, 1.0f / (BB * NN));
    k_bn_act<<<BB * 64 * NN / 4 / 256, 256, 0, stream>>>(fpre, stats + 384, out, 10, 0.0f);

    hipMemcpyAsync(out + (size_t)BB * CO * NN, coords, (size_t)BB * 3 * NN * 4,
                   hipMemcpyDeviceToDevice, stream);
}